// Round 9
// baseline (133.256 us; speedup 1.0000x reference)
//
#include <hip/hip_runtime.h>
#include <cstdint>
#include <cstddef>

// Problem constants
#define NB 4
#define SS 2048
#define DM 1024
#define DH 64
#define MROWS (NB*SS)      // 8192
#define NALL  (2*DH + DM)  // 1152

typedef __attribute__((ext_vector_type(8))) short bf16x8;
typedef __attribute__((ext_vector_type(4))) float f32x4;
typedef __attribute__((ext_vector_type(4))) unsigned short us4;

__device__ __forceinline__ unsigned short f2bf(float f){
  unsigned u = __builtin_bit_cast(unsigned, f);
  u = (u + 0x7fffu + ((u >> 16) & 1u)) >> 16;   // RNE
  return (unsigned short)u;
}
__device__ __forceinline__ float bf2f(unsigned short h){
  unsigned u = ((unsigned)h) << 16;
  return __builtin_bit_cast(float, u);
}
__device__ __forceinline__ f32x4 mfma16(bf16x8 a, bf16x8 b, f32x4 c){
  return __builtin_amdgcn_mfma_f32_16x16x32_bf16(a, b, c, 0, 0, 0);
}

// ---------------- prep: split x into bf16 hi/lo ----------------
__global__ void prep_x_kernel(const float* __restrict__ x,
                              unsigned short* __restrict__ xh,
                              unsigned short* __restrict__ xl){
  const int n4 = MROWS*DM/4;
  for (int i = blockIdx.x*blockDim.x + threadIdx.x; i < n4; i += gridDim.x*blockDim.x){
    float4 v = reinterpret_cast<const float4*>(x)[i];
    float f[4] = {v.x, v.y, v.z, v.w};
    us4 h, lo;
    #pragma unroll
    for (int j = 0; j < 4; ++j){
      unsigned short hh = f2bf(f[j]);
      h[j]  = hh;
      lo[j] = f2bf(f[j] - bf2f(hh));
    }
    reinterpret_cast<us4*>(xh)[i] = h;
    reinterpret_cast<us4*>(xl)[i] = lo;
  }
}

// ---------------- prep: weights + bias ----------------
__global__ void prep_w_kernel(const float* __restrict__ wq, const float* __restrict__ wk,
                              const float* __restrict__ wv,
                              const float* __restrict__ bq, const float* __restrict__ bk,
                              const float* __restrict__ bv,
                              unsigned short* __restrict__ Whi, unsigned short* __restrict__ Wlo,
                              float* __restrict__ bias_all){
  const int n = NALL*DM;
  for (int i = blockIdx.x*blockDim.x + threadIdx.x; i < n; i += gridDim.x*blockDim.x){
    const int r = i >> 10, c = i & 1023;
    float v;
    if (r < 64)       v = wq[r*1024 + c];
    else if (r < 128) v = wk[(r-64)*1024 + c];
    else              v = wv[(r-128)*1024 + c];
    const unsigned short h = f2bf(v);
    Whi[i] = h;
    if (r < 128) Wlo[i] = f2bf(v - bf2f(h));
    if (i < NALL) bias_all[i] = (i < 64) ? bq[i] : (i < 128) ? bk[i-64] : bv[i-128];
  }
}

// Stage one 128x32 A-tile + 128x32 B-tile into LDS buffer (4 gload_lds / thread).
// Bank-conflict swizzle (both-sides, rule #21): LDS chunk c holds global
// (row=c>>2, kq=(c&3)^((row>>1)&3)) — same 64B row segment, lanes permuted,
// so global coalescing is unchanged; the read side XORs the same term.
// Measured: SQ_LDS_BANK_CONFLICT = 0 with this layout (round 8).
#define STAGE_TILES(TAbuf, TBbuf, ABASE, BBASE, ASTRIDE, BSTRIDE, K0) do{        \
    _Pragma("unroll")                                                            \
    for (int p_ = 0; p_ < 2; ++p_){                                              \
      const int c_ = tid + p_*256;                                               \
      const int row_ = c_ >> 2;                                                  \
      const int kq_ = (c_ & 3) ^ ((row_ >> 1) & 3);                              \
      const int lbase_ = w*1024 + p_*4096;                                       \
      __builtin_amdgcn_global_load_lds(                                          \
        (const __attribute__((address_space(1))) void*)((ABASE) + ((size_t)row_*(ASTRIDE) + (K0) + kq_*8)), \
        (__attribute__((address_space(3))) void*)((char*)(TAbuf) + lbase_), 16, 0, 0); \
      __builtin_amdgcn_global_load_lds(                                          \
        (const __attribute__((address_space(1))) void*)((BBASE) + ((size_t)row_*(BSTRIDE) + (K0) + kq_*8)), \
        (__attribute__((address_space(3))) void*)((char*)(TBbuf) + lbase_), 16, 0, 0); \
    } }while(0)

// Compute one 32-K sub-tile from LDS (conflict-free swizzled reads).
#define COMPUTE_SUBTILE(TAbuf, TBbuf) do{                                        \
    bf16x8 af_[4], bf_[4];                                                       \
    _Pragma("unroll")                                                            \
    for (int mi_ = 0; mi_ < 4; ++mi_){                                           \
      const int r_ = wr*64 + mi_*16 + lc;                                        \
      af_[mi_] = *reinterpret_cast<const bf16x8*>((const char*)(TAbuf) + r_*64 + xq); \
    }                                                                            \
    _Pragma("unroll")                                                            \
    for (int ni_ = 0; ni_ < 4; ++ni_){                                           \
      const int r_ = wc*64 + ni_*16 + lc;                                        \
      bf_[ni_] = *reinterpret_cast<const bf16x8*>((const char*)(TBbuf) + r_*64 + xq); \
    }                                                                            \
    __builtin_amdgcn_s_setprio(1);                                               \
    _Pragma("unroll")                                                            \
    for (int mi_ = 0; mi_ < 4; ++mi_)                                            \
      _Pragma("unroll")                                                          \
      for (int ni_ = 0; ni_ < 4; ++ni_)                                          \
        acc[mi_][ni_] = mfma16(af_[mi_], bf_[ni_], acc[mi_][ni_]);               \
    __builtin_amdgcn_s_setprio(0);                                               \
  }while(0)

// ---------------- QKV GEMM: split-K + XCD-clustered + BK=64 paired pipeline ----------------
// 704 blocks = 64 mtiles x 11 equal jobs; XCD x owns mtiles [8x,8x+8) (L2 locality).
//   j 0..7  : V ntile j   -> Vt (bias fused)
//   j 8..10 : QK pass j-8 -> f32 partial QKpart[p]  (p0=xh.Whi, p1=xh.Wlo, p2=xl.Whi)
// K-loop: 2 buffers x 2 sub-tiles (64 KB LDS, 2 blocks/CU). Per 64-K step:
//   vmcnt(0) [pair t landed; issued a full iteration ago => ~0 stall]
//   -> s_barrier -> stage pair t+1 -> compute 2 sub-tiles (32 MFMA).
// ONE barrier per 64-K (was 2 per 32-K): 4x less sync ceremony per byte.
// Overwrite safety: stage(t+1) targets the buffer read at t-1, whose readers
// passed barrier(t) only after lgkm-complete ds_reads.
__global__ __launch_bounds__(256) void qkv_split_kernel(
    const unsigned short* __restrict__ xh, const unsigned short* __restrict__ xl,
    const unsigned short* __restrict__ Whi, const unsigned short* __restrict__ Wlo,
    const float* __restrict__ bias_all,
    unsigned short* __restrict__ Vt, float* __restrict__ QKpart)
{
  __shared__ unsigned short tA[2][2][128*32];   // [buf][ks] 4 x 8 KB
  __shared__ unsigned short tB[2][2][128*32];
  const int bx = blockIdx.x;
  const int xcd  = bx & 7;
  const int slot = bx >> 3;              // 0..87
  const int mtile = xcd*8 + (slot & 7);
  const int j = slot >> 3;               // 0..10
  const int m0 = mtile*128;
  const int tid = threadIdx.x;
  const int l = tid & 63, w = tid >> 6;
  const int lr = l >> 4, lc = l & 15;
  const int wr = w >> 1, wc = w & 1;
  const int xq = (lr ^ ((lc >> 1) & 3))*16;   // swizzled k-quad byte offset (lane-const)

  const unsigned short* Ab;
  const unsigned short* Bb;
  if (j < 8){ Ab = xh; Bb = Whi + (size_t)(j+1)*128*DM; }
  else {
    const int p = j - 8;
    Ab = (p == 2) ? xl : xh;
    Bb = (p == 1) ? Wlo : Whi;
  }
  const unsigned short* Abase = Ab + (size_t)m0*DM;

  f32x4 acc[4][4] = {};
  STAGE_TILES(tA[0][0], tB[0][0], Abase, Bb, DM, DM, 0);
  STAGE_TILES(tA[0][1], tB[0][1], Abase, Bb, DM, DM, 32);
  for (int t = 0; t < 16; ++t){
    const int cur = t & 1;
    asm volatile("s_waitcnt vmcnt(0)" ::: "memory");
    __builtin_amdgcn_s_barrier();
    __builtin_amdgcn_sched_barrier(0);
    if (t + 1 < 16){
      STAGE_TILES(tA[cur^1][0], tB[cur^1][0], Abase, Bb, DM, DM, (t+1)*64);
      STAGE_TILES(tA[cur^1][1], tB[cur^1][1], Abase, Bb, DM, DM, (t+1)*64 + 32);
    }
    COMPUTE_SUBTILE(tA[cur][0], tB[cur][0]);
    COMPUTE_SUBTILE(tA[cur][1], tB[cur][1]);
  }

  if (j < 8){
    const int n0 = (j+1)*128;
    #pragma unroll
    for (int ni = 0; ni < 4; ++ni){
      const int col = n0 + wc*64 + ni*16 + lc;
      const float bias = bias_all[col];
      const int vc = col - 128;
      #pragma unroll
      for (int mi = 0; mi < 4; ++mi){
        const int rowb = m0 + wr*64 + mi*16 + lr*4;
        const int b  = rowb >> 11;
        const int s  = rowb & 2047;
        us4 pk;
        #pragma unroll
        for (int i = 0; i < 4; ++i) pk[i] = f2bf(acc[mi][ni][i] + bias);
        *reinterpret_cast<us4*>(&Vt[((size_t)b*DM + vc)*SS + s]) = pk;
      }
    }
  } else {
    float* dst = QKpart + (size_t)(j-8)*MROWS*128;
    #pragma unroll
    for (int mi = 0; mi < 4; ++mi)
      #pragma unroll
      for (int i = 0; i < 4; ++i){
        const int row = m0 + wr*64 + mi*16 + lr*4 + i;
        #pragma unroll
        for (int ni = 0; ni < 4; ++ni){
          const int col = wc*64 + ni*16 + lc;
          dst[(size_t)row*128 + col] = acc[mi][ni][i];
        }
      }
  }
}

// ---------------- combine the 3 QK partials -> Qh/Ql/Kh/Kl ----------------
__global__ __launch_bounds__(256) void qk_combine_kernel(
    const float* __restrict__ QKpart, const float* __restrict__ bias_all,
    unsigned short* __restrict__ Qh, unsigned short* __restrict__ Ql,
    unsigned short* __restrict__ Kh, unsigned short* __restrict__ Kl)
{
  const int t = blockIdx.x*256 + threadIdx.x;    // 0..262143 -> (row, c4)
  const int row = t >> 5, c4 = t & 31;
  const int col0 = c4*4;
  us4 h, lo;
  #pragma unroll
  for (int i = 0; i < 4; ++i){
    const int col = col0 + i;
    const size_t o = (size_t)row*128 + col;
    float s = QKpart[o] + QKpart[(size_t)MROWS*128 + o]
            + QKpart[(size_t)2*MROWS*128 + o] + bias_all[col];
    const unsigned short hh = f2bf(s);
    h[i]  = hh;
    lo[i] = f2bf(s - bf2f(hh));
  }
  if (col0 < 64){
    *reinterpret_cast<us4*>(&Qh[(size_t)row*DH + col0]) = h;
    *reinterpret_cast<us4*>(&Ql[(size_t)row*DH + col0]) = lo;
  } else {
    *reinterpret_cast<us4*>(&Kh[(size_t)row*DH + col0 - 64]) = h;
    *reinterpret_cast<us4*>(&Kl[(size_t)row*DH + col0 - 64]) = lo;
  }
}

// ---------------- QKV GEMM fallback (3-pass, used only if ws too small) ----------------
__global__ __launch_bounds__(256) void qkv_gemm_kernel(
    const unsigned short* __restrict__ xh, const unsigned short* __restrict__ xl,
    const unsigned short* __restrict__ Whi, const unsigned short* __restrict__ Wlo,
    const float* __restrict__ bias_all,
    unsigned short* __restrict__ Qh, unsigned short* __restrict__ Ql,
    unsigned short* __restrict__ Kh, unsigned short* __restrict__ Kl,
    unsigned short* __restrict__ Vt)
{
  __shared__ unsigned short tA[128*32];
  __shared__ unsigned short tB[128*32];
  const int bx = blockIdx.x;
  const int mtile = bx & 63;
  const int ntile = bx >> 6;
  const int m0 = mtile*128, n0 = ntile*128;
  const int tid = threadIdx.x;
  const int l = tid & 63, w = tid >> 6;
  const int lr = l >> 4, lc = l & 15;
  const int wr = w >> 1, wc = w & 1;

  f32x4 acc[4][4] = {};
  const int npass = (ntile == 0) ? 3 : 1;
  for (int pass = 0; pass < npass; ++pass){
    const unsigned short* Ab = (pass == 2) ? xl : xh;
    const unsigned short* Bb = (pass == 1) ? Wlo : (Whi + (size_t)n0*DM);
    for (int k0 = 0; k0 < DM; k0 += 32){
      __syncthreads();
      #pragma unroll
      for (int p = 0; p < 2; ++p){
        const int c   = tid + p*256;
        const int row = c >> 2, kq = c & 3;
        const unsigned short* ga = Ab + ((size_t)(m0+row)*DM + k0 + kq*8);
        const unsigned short* gb = Bb + ((size_t)row*DM     + k0 + kq*8);
        const int lbase = w*1024 + p*4096;
        __builtin_amdgcn_global_load_lds(
            (const __attribute__((address_space(1))) void*)ga,
            (__attribute__((address_space(3))) void*)((char*)tA + lbase), 16, 0, 0);
        __builtin_amdgcn_global_load_lds(
            (const __attribute__((address_space(1))) void*)gb,
            (__attribute__((address_space(3))) void*)((char*)tB + lbase), 16, 0, 0);
      }
      __syncthreads();
      bf16x8 af[4], bfr[4];
      #pragma unroll
      for (int mi = 0; mi < 4; ++mi){
        const int r = wr*64 + mi*16 + lc;
        af[mi] = *reinterpret_cast<const bf16x8*>((const char*)tA + r*64 + lr*16);
      }
      #pragma unroll
      for (int ni = 0; ni < 4; ++ni){
        const int r = wc*64 + ni*16 + lc;
        bfr[ni] = *reinterpret_cast<const bf16x8*>((const char*)tB + r*64 + lr*16);
      }
      #pragma unroll
      for (int mi = 0; mi < 4; ++mi)
        #pragma unroll
        for (int ni = 0; ni < 4; ++ni)
          acc[mi][ni] = mfma16(af[mi], bfr[ni], acc[mi][ni]);
    }
  }

  #pragma unroll
  for (int ni = 0; ni < 4; ++ni){
    const int col = n0 + wc*64 + ni*16 + lc;
    const float bias = bias_all[col];
    #pragma unroll
    for (int mi = 0; mi < 4; ++mi){
      const int rowb = m0 + wr*64 + mi*16 + lr*4;
      if (ntile > 0){
        const int vc = col - 128;
        const int b  = rowb >> 11;
        const int s  = rowb & 2047;
        us4 pk;
        #pragma unroll
        for (int i = 0; i < 4; ++i) pk[i] = f2bf(acc[mi][ni][i] + bias);
        *reinterpret_cast<us4*>(&Vt[((size_t)b*DM + vc)*SS + s]) = pk;
      } else {
        #pragma unroll
        for (int i = 0; i < 4; ++i){
          const int row = rowb + i;
          const float v = acc[mi][ni][i] + bias;
          const unsigned short h   = f2bf(v);
          const unsigned short lo2 = f2bf(v - bf2f(h));
          if (col < DH){
            Qh[(size_t)row*DH + col] = h;
            Ql[(size_t)row*DH + col] = lo2;
          } else {
            Kh[(size_t)row*DH + col - DH] = h;
            Kl[(size_t)row*DH + col - DH] = lo2;
          }
        }
      }
    }
  }
}

// ---------------- diag: per-row softmax anchor M_r = q_r.k_r + 20, zero lpart ----------------
__global__ __launch_bounds__(256) void diag_kernel(
    const unsigned short* __restrict__ Qh, const unsigned short* __restrict__ Ql,
    const unsigned short* __restrict__ Kh, const unsigned short* __restrict__ Kl,
    float* __restrict__ Mrow, float* __restrict__ lpart)
{
  const int r = blockIdx.x*256 + threadIdx.x;   // 0..8191
  float dot = 0.f;
  #pragma unroll
  for (int c = 0; c < 8; ++c){
    bf16x8 a  = *reinterpret_cast<const bf16x8*>(Qh + (size_t)r*DH + c*8);
    bf16x8 al = *reinterpret_cast<const bf16x8*>(Ql + (size_t)r*DH + c*8);
    bf16x8 bh = *reinterpret_cast<const bf16x8*>(Kh + (size_t)r*DH + c*8);
    bf16x8 bl = *reinterpret_cast<const bf16x8*>(Kl + (size_t)r*DH + c*8);
    #pragma unroll
    for (int j = 0; j < 8; ++j)
      dot += (bf2f((unsigned short)a[j]) + bf2f((unsigned short)al[j])) *
             (bf2f((unsigned short)bh[j]) + bf2f((unsigned short)bl[j]));
  }
  Mrow[r] = dot + 20.0f;
  #pragma unroll
  for (int kc = 0; kc < 8; ++kc) lpart[(size_t)r*8 + kc] = 0.f;
}

// ---------------- scores: P = exp(S - M_r) bf16, per-chunk row sums ----------------
__global__ __launch_bounds__(512) void scores_kernel(
    const unsigned short* __restrict__ Qh, const unsigned short* __restrict__ Ql,
    const unsigned short* __restrict__ Kh, const unsigned short* __restrict__ Kl,
    const float* __restrict__ Mrow,
    unsigned short* __restrict__ Pbuf, float* __restrict__ lpart)
{
  __shared__ float ws_s[8][32];
  const int t = blockIdx.x, b = blockIdx.y;
  int g = 0;
  while (g < 7 && 4*(g+1)*(g+2) <= t) ++g;
  const int base = 4*g*(g+1);
  const int qt = 8*g + (t - base)/(g+1);
  const int kc = (t - base)%(g+1);
  const int q0 = qt*32, kbase = kc*256;
  const int tid = threadIdx.x, l = tid & 63, w = tid >> 6;
  const int lr = l >> 4, lc = l & 15;
  const int kw0 = kbase + w*32;
  const float L2E = 1.4426950408889634f;

  bf16x8 qh[2][2], qlo[2][2], kh[2][2], kl2[2][2];
  #pragma unroll
  for (int qi = 0; qi < 2; ++qi)
    #pragma unroll
    for (int ks = 0; ks < 2; ++ks){
      const size_t off = (size_t)(b*SS + q0 + qi*16 + lc)*DH + ks*32 + lr*8;
      qh[qi][ks]  = *reinterpret_cast<const bf16x8*>(&Qh[off]);
      qlo[qi][ks] = *reinterpret_cast<const bf16x8*>(&Ql[off]);
    }
  #pragma unroll
  for (int ki = 0; ki < 2; ++ki)
    #pragma unroll
    for (int ks = 0; ks < 2; ++ks){
      const size_t off = (size_t)(b*SS + kw0 + ki*16 + lc)*DH + ks*32 + lr*8;
      kh[ki][ks]  = *reinterpret_cast<const bf16x8*>(&Kh[off]);
      kl2[ki][ks] = *reinterpret_cast<const bf16x8*>(&Kl[off]);
    }

  f32x4 sa[2][2] = {};
  #pragma unroll
  for (int qi = 0; qi < 2; ++qi)
    #pragma unroll
    for (int ki = 0; ki < 2; ++ki)
      #pragma unroll
      for (int ks = 0; ks < 2; ++ks){
        sa[qi][ki] = mfma16(qh[qi][ks],  kh[ki][ks],  sa[qi][ki]);
        sa[qi][ki] = mfma16(qh[qi][ks],  kl2[ki][ks], sa[qi][ki]);
        sa[qi][ki] = mfma16(qlo[qi][ks], kh[ki][ks],  sa[qi][ki]);
      }

  float Mv[2][4];
  #pragma unroll
  for (int qi = 0; qi < 2; ++qi)
    #pragma unroll
    for (int i = 0; i < 4; ++i)
      Mv[qi][i] = Mrow[b*SS + q0 + qi*16 + lr*4 + i];

  const bool diagblk = (kc == (qt >> 3));
  float psum[2][4] = {};
  #pragma unroll
  for (int qi = 0; qi < 2; ++qi)
    #pragma unroll
    for (int ki = 0; ki < 2; ++ki)
      #pragma unroll
      for (int i = 0; i < 4; ++i){
        const int qrow = qi*16 + lr*4 + i;
        const int kcol = w*32 + ki*16 + lc;
        float p;
        if (diagblk && (kbase + kcol > q0 + qrow)) p = 0.f;
        else p = exp2f((sa[qi][ki][i] - Mv[qi][i])*L2E);
        Pbuf[(size_t)(b*SS + q0 + qrow)*SS + kbase + kcol] = f2bf(p);
        psum[qi][i] += p;
      }

  #pragma unroll
  for (int qi = 0; qi < 2; ++qi)
    #pragma unroll
    for (int i = 0; i < 4; ++i){
      float s = psum[qi][i];
      #pragma unroll
      for (int m = 1; m < 16; m <<= 1) s += __shfl_xor(s, m);
      psum[qi][i] = s;
    }
  if (lc == 0){
    #pragma unroll
    for (int qi = 0; qi < 2; ++qi)
      #pragma unroll
      for (int i = 0; i < 4; ++i)
        ws_s[w][qi*16 + lr*4 + i] = psum[qi][i];
  }
  __syncthreads();
  if (tid < 32){
    float s = 0.f;
    #pragma unroll
    for (int w2 = 0; w2 < 8; ++w2) s += ws_s[w2][tid];
    lpart[(size_t)(b*SS + q0 + tid)*8 + kc] = s;
  }
}

// ---------------- combine: l_r = sum of chunk partials ----------------
__global__ __launch_bounds__(256) void combine_kernel(const float* __restrict__ lpart,
                                                      float* __restrict__ lfin){
  const int r = blockIdx.x*256 + threadIdx.x;
  float s = 0.f;
  #pragma unroll
  for (int kc = 0; kc < 8; ++kc) s += lpart[(size_t)r*8 + kc];
  lfin[r] = s;
}

// ---------------- PV GEMM + XCD-clustered + BK=64 paired pipeline: out = (P @ V) / l ----
// 512 blocks = 64 per XCD; XCD x owns (batch = x>>1, nt-group = x&1); within-XCD
// mt paired k/(15-k) per CU. kend = (mt/2+1)*256 covers every row's diagonal
// chunk (masked region zero-filled by scores_kernel). NPAIR = (mt/2+1)*4.
__global__ __launch_bounds__(256) void pv_kernel(
    const unsigned short* __restrict__ Pbuf, const unsigned short* __restrict__ Vt,
    const float* __restrict__ lfin, float* __restrict__ out)
{
  __shared__ unsigned short tA[2][2][128*32];
  __shared__ unsigned short tB[2][2][128*32];
  const int bx = blockIdx.x;           // 0..511
  const int xcd  = bx & 7;
  const int slot = bx >> 3;            // 0..63
  const int b   = xcd >> 1;
  const int ntg = xcd & 1;
  const int nt  = ntg*4 + (slot & 3);
  const int mt  = (slot < 32) ? (15 - (slot >> 2)) : ((slot - 32) >> 2);
  const int m0 = mt*128, n0 = nt*128;
  const int tid = threadIdx.x;
  const int l = tid & 63, w = tid >> 6;
  const int lr = l >> 4, lc = l & 15;
  const int wr = w >> 1, wc = w & 1;
  const int xq = (lr ^ ((lc >> 1) & 3))*16;

  const unsigned short* Ab = Pbuf + (size_t)(b*SS + m0)*SS;
  const unsigned short* Bb = Vt   + (size_t)(b*DM + n0)*SS;

  f32x4 acc[4][4] = {};
  const int NPAIR = (mt/2 + 1)*4;      // 64-K steps
  STAGE_TILES(tA[0][0], tB[0][0], Ab, Bb, SS, SS, 0);
  STAGE_TILES(tA[0][1], tB[0][1], Ab, Bb, SS, SS, 32);
  for (int t = 0; t < NPAIR; ++t){
    const int cur = t & 1;
    asm volatile("s_waitcnt vmcnt(0)" ::: "memory");
    __builtin_amdgcn_s_barrier();
    __builtin_amdgcn_sched_barrier(0);
    if (t + 1 < NPAIR){
      STAGE_TILES(tA[cur^1][0], tB[cur^1][0], Ab, Bb, SS, SS, (t+1)*64);
      STAGE_TILES(tA[cur^1][1], tB[cur^1][1], Ab, Bb, SS, SS, (t+1)*64 + 32);
    }
    COMPUTE_SUBTILE(tA[cur][0], tB[cur][0]);
    COMPUTE_SUBTILE(tA[cur][1], tB[cur][1]);
  }

  #pragma unroll
  for (int mi = 0; mi < 4; ++mi){
    #pragma unroll
    for (int i = 0; i < 4; ++i){
      const int row = m0 + wr*64 + mi*16 + lr*4 + i;
      const float linv = 1.0f / lfin[b*SS + row];
      #pragma unroll
      for (int ni = 0; ni < 4; ++ni){
        const int col = n0 + wc*64 + ni*16 + lc;
        out[(size_t)(b*SS + row)*DM + col] = acc[mi][ni][i]*linv;
      }
    }
  }
}

// ---------------- launcher ----------------
extern "C" void kernel_launch(void* const* d_in, const int* in_sizes, int n_in,
                              void* d_out, int out_size, void* d_ws, size_t ws_size,
                              hipStream_t stream)
{
  const float* x  = (const float*)d_in[0];
  const float* wq = (const float*)d_in[1];
  const float* bq = (const float*)d_in[2];
  const float* wk = (const float*)d_in[3];
  const float* bk = (const float*)d_in[4];
  const float* wv = (const float*)d_in[5];
  const float* bv = (const float*)d_in[6];
  float* out = (float*)d_out;

  char* ws = (char*)d_ws;
  unsigned short* xh  = (unsigned short*)(ws + 0);          // 16,777,216
  unsigned short* xl  = (unsigned short*)(ws + 16777216);   // 16,777,216
  unsigned short* Pbuf= (unsigned short*)(ws + 0);          // 33,554,432 (alias)
  unsigned short* Whi = (unsigned short*)(ws + 33554432);   //  2,359,296
  unsigned short* Wlo = (unsigned short*)(ws + 35913728);   //    262,144
  float* bias_all     = (float*)(ws + 36175872);            //      4,608
  unsigned short* Qh  = (unsigned short*)(ws + 36180480);   //  1,048,576
  unsigned short* Ql  = (unsigned short*)(ws + 37229056);   //  1,048,576
  unsigned short* Kh  = (unsigned short*)(ws + 38277632);   //  1,048,576
  unsigned short* Kl  = (unsigned short*)(ws + 39326208);   //  1,048,576
  unsigned short* Vt  = (unsigned short*)(ws + 40374784);   // 16,777,216
  float* Mrow         = (float*)(ws + 57152000);            //     32,768
  float* lpart        = (float*)(ws + 57184768);            //    262,144
  float* lfin         = (float*)(ws + 57446912);            //     32,768
  const size_t QKPART_OFF = 57479680;
  float* QKpart       = (float*)(ws + QKPART_OFF);          // 12,582,912
  const size_t NEED = QKPART_OFF + (size_t)3*MROWS*128*4;   // 70,062,592

  hipLaunchKernelGGL(prep_x_kernel, dim3(2048), dim3(256), 0, stream, x, xh, xl);
  hipLaunchKernelGGL(prep_w_kernel, dim3(1184), dim3(256), 0, stream,
                     wq, wk, wv, bq, bk, bv, Whi, Wlo, bias_all);
  if (ws_size >= NEED){
    hipLaunchKernelGGL(qkv_split_kernel, dim3(704), dim3(256), 0, stream,
                       xh, xl, Whi, Wlo, bias_all, Vt, QKpart);
    hipLaunchKernelGGL(qk_combine_kernel, dim3(1024), dim3(256), 0, stream,
                       QKpart, bias_all, Qh, Ql, Kh, Kl);
  } else {
    hipLaunchKernelGGL(qkv_gemm_kernel, dim3(576), dim3(256), 0, stream,
                       xh, xl, Whi, Wlo, bias_all, Qh, Ql, Kh, Kl, Vt);
  }
  hipLaunchKernelGGL(diag_kernel, dim3(32), dim3(256), 0, stream,
                     Qh, Ql, Kh, Kl, Mrow, lpart);
  hipLaunchKernelGGL(scores_kernel, dim3(288, 4), dim3(512), 0, stream,
                     Qh, Ql, Kh, Kl, Mrow, Pbuf, lpart);
  hipLaunchKernelGGL(combine_kernel, dim3(32), dim3(256), 0, stream, lpart, lfin);
  hipLaunchKernelGGL(pv_kernel, dim3(512), dim3(256), 0, stream, Pbuf, Vt, lfin, out);
}

// Round 10
// 123.058 us; speedup vs baseline: 1.0829x; 1.0829x over previous
//
#include <hip/hip_runtime.h>
#include <cstdint>
#include <cstddef>

// Problem constants
#define NB 4
#define SS 2048
#define DM 1024
#define DH 64
#define MROWS (NB*SS)      // 8192
#define NALL  (2*DH + DM)  // 1152

typedef __attribute__((ext_vector_type(8))) short bf16x8;
typedef __attribute__((ext_vector_type(4))) float f32x4;
typedef __attribute__((ext_vector_type(4))) unsigned short us4;

__device__ __forceinline__ unsigned short f2bf(float f){
  unsigned u = __builtin_bit_cast(unsigned, f);
  u = (u + 0x7fffu + ((u >> 16) & 1u)) >> 16;   // RNE
  return (unsigned short)u;
}
__device__ __forceinline__ float bf2f(unsigned short h){
  unsigned u = ((unsigned)h) << 16;
  return __builtin_bit_cast(float, u);
}
__device__ __forceinline__ f32x4 mfma16(bf16x8 a, bf16x8 b, f32x4 c){
  return __builtin_amdgcn_mfma_f32_16x16x32_bf16(a, b, c, 0, 0, 0);
}

// ---------------- fused prep: x hi/lo split + weights + bias (one launch) ----------------
__global__ void prep_kernel(const float* __restrict__ x,
                            const float* __restrict__ wq, const float* __restrict__ wk,
                            const float* __restrict__ wv,
                            const float* __restrict__ bq, const float* __restrict__ bk,
                            const float* __restrict__ bv,
                            unsigned short* __restrict__ xh, unsigned short* __restrict__ xl,
                            unsigned short* __restrict__ Whi, unsigned short* __restrict__ Wlo,
                            float* __restrict__ bias_all){
  const int n4 = MROWS*DM/4;
  for (int i = blockIdx.x*blockDim.x + threadIdx.x; i < n4; i += gridDim.x*blockDim.x){
    float4 v = reinterpret_cast<const float4*>(x)[i];
    float f[4] = {v.x, v.y, v.z, v.w};
    us4 h, lo;
    #pragma unroll
    for (int j = 0; j < 4; ++j){
      unsigned short hh = f2bf(f[j]);
      h[j]  = hh;
      lo[j] = f2bf(f[j] - bf2f(hh));
    }
    reinterpret_cast<us4*>(xh)[i] = h;
    reinterpret_cast<us4*>(xl)[i] = lo;
  }
  const int n = NALL*DM;
  for (int i = blockIdx.x*blockDim.x + threadIdx.x; i < n; i += gridDim.x*blockDim.x){
    const int r = i >> 10, c = i & 1023;
    float v;
    if (r < 64)       v = wq[r*1024 + c];
    else if (r < 128) v = wk[(r-64)*1024 + c];
    else              v = wv[(r-128)*1024 + c];
    const unsigned short h = f2bf(v);
    Whi[i] = h;
    if (r < 128) Wlo[i] = f2bf(v - bf2f(h));
    if (i < NALL) bias_all[i] = (i < 64) ? bq[i] : (i < 128) ? bk[i-64] : bv[i-128];
  }
}

// Stage one 128x32 A-tile + 128x32 B-tile into LDS buffer (4 gload_lds / thread).
// Bank-conflict swizzle (both-sides, rule #21): LDS chunk c holds global
// (row=c>>2, kq=(c&3)^((row>>1)&3)) — same 64B row segment, lanes permuted,
// so global coalescing is unchanged; the read side XORs the same term.
// Measured: SQ_LDS_BANK_CONFLICT = 0 with this layout (round 8).
#define STAGE_TILES(TAbuf, TBbuf, ABASE, BBASE, ASTRIDE, BSTRIDE, K0) do{        \
    _Pragma("unroll")                                                            \
    for (int p_ = 0; p_ < 2; ++p_){                                              \
      const int c_ = tid + p_*256;                                               \
      const int row_ = c_ >> 2;                                                  \
      const int kq_ = (c_ & 3) ^ ((row_ >> 1) & 3);                              \
      const int lbase_ = w*1024 + p_*4096;                                       \
      __builtin_amdgcn_global_load_lds(                                          \
        (const __attribute__((address_space(1))) void*)((ABASE) + ((size_t)row_*(ASTRIDE) + (K0) + kq_*8)), \
        (__attribute__((address_space(3))) void*)((char*)(TAbuf) + lbase_), 16, 0, 0); \
      __builtin_amdgcn_global_load_lds(                                          \
        (const __attribute__((address_space(1))) void*)((BBASE) + ((size_t)row_*(BSTRIDE) + (K0) + kq_*8)), \
        (__attribute__((address_space(3))) void*)((char*)(TBbuf) + lbase_), 16, 0, 0); \
    } }while(0)

// Compute one 32-K sub-tile from LDS (conflict-free swizzled reads).
#define COMPUTE_SUBTILE(TAbuf, TBbuf) do{                                        \
    bf16x8 af_[4], bf_[4];                                                       \
    _Pragma("unroll")                                                            \
    for (int mi_ = 0; mi_ < 4; ++mi_){                                           \
      const int r_ = wr*64 + mi_*16 + lc;                                        \
      af_[mi_] = *reinterpret_cast<const bf16x8*>((const char*)(TAbuf) + r_*64 + xq); \
    }                                                                            \
    _Pragma("unroll")                                                            \
    for (int ni_ = 0; ni_ < 4; ++ni_){                                           \
      const int r_ = wc*64 + ni_*16 + lc;                                        \
      bf_[ni_] = *reinterpret_cast<const bf16x8*>((const char*)(TBbuf) + r_*64 + xq); \
    }                                                                            \
    __builtin_amdgcn_s_setprio(1);                                               \
    _Pragma("unroll")                                                            \
    for (int mi_ = 0; mi_ < 4; ++mi_)                                            \
      _Pragma("unroll")                                                          \
      for (int ni_ = 0; ni_ < 4; ++ni_)                                          \
        acc[mi_][ni_] = mfma16(af_[mi_], bf_[ni_], acc[mi_][ni_]);               \
    __builtin_amdgcn_s_setprio(0);                                               \
  }while(0)

// ---------------- QKV GEMM: split-K + XCD-clustered + BK=64 paired pipeline (round-9) ----
__global__ __launch_bounds__(256) void qkv_split_kernel(
    const unsigned short* __restrict__ xh, const unsigned short* __restrict__ xl,
    const unsigned short* __restrict__ Whi, const unsigned short* __restrict__ Wlo,
    const float* __restrict__ bias_all,
    unsigned short* __restrict__ Vt, float* __restrict__ QKpart)
{
  __shared__ unsigned short tA[2][2][128*32];   // [buf][ks] 4 x 8 KB
  __shared__ unsigned short tB[2][2][128*32];
  const int bx = blockIdx.x;
  const int xcd  = bx & 7;
  const int slot = bx >> 3;              // 0..87
  const int mtile = xcd*8 + (slot & 7);
  const int j = slot >> 3;               // 0..10
  const int m0 = mtile*128;
  const int tid = threadIdx.x;
  const int l = tid & 63, w = tid >> 6;
  const int lr = l >> 4, lc = l & 15;
  const int wr = w >> 1, wc = w & 1;
  const int xq = (lr ^ ((lc >> 1) & 3))*16;   // swizzled k-quad byte offset (lane-const)

  const unsigned short* Ab;
  const unsigned short* Bb;
  if (j < 8){ Ab = xh; Bb = Whi + (size_t)(j+1)*128*DM; }
  else {
    const int p = j - 8;
    Ab = (p == 2) ? xl : xh;
    Bb = (p == 1) ? Wlo : Whi;
  }
  const unsigned short* Abase = Ab + (size_t)m0*DM;

  f32x4 acc[4][4] = {};
  STAGE_TILES(tA[0][0], tB[0][0], Abase, Bb, DM, DM, 0);
  STAGE_TILES(tA[0][1], tB[0][1], Abase, Bb, DM, DM, 32);
  for (int t = 0; t < 16; ++t){
    const int cur = t & 1;
    asm volatile("s_waitcnt vmcnt(0)" ::: "memory");
    __builtin_amdgcn_s_barrier();
    __builtin_amdgcn_sched_barrier(0);
    if (t + 1 < 16){
      STAGE_TILES(tA[cur^1][0], tB[cur^1][0], Abase, Bb, DM, DM, (t+1)*64);
      STAGE_TILES(tA[cur^1][1], tB[cur^1][1], Abase, Bb, DM, DM, (t+1)*64 + 32);
    }
    COMPUTE_SUBTILE(tA[cur][0], tB[cur][0]);
    COMPUTE_SUBTILE(tA[cur][1], tB[cur][1]);
  }

  if (j < 8){
    const int n0 = (j+1)*128;
    #pragma unroll
    for (int ni = 0; ni < 4; ++ni){
      const int col = n0 + wc*64 + ni*16 + lc;
      const float bias = bias_all[col];
      const int vc = col - 128;
      #pragma unroll
      for (int mi = 0; mi < 4; ++mi){
        const int rowb = m0 + wr*64 + mi*16 + lr*4;
        const int b  = rowb >> 11;
        const int s  = rowb & 2047;
        us4 pk;
        #pragma unroll
        for (int i = 0; i < 4; ++i) pk[i] = f2bf(acc[mi][ni][i] + bias);
        *reinterpret_cast<us4*>(&Vt[((size_t)b*DM + vc)*SS + s]) = pk;
      }
    }
  } else {
    float* dst = QKpart + (size_t)(j-8)*MROWS*128;
    #pragma unroll
    for (int mi = 0; mi < 4; ++mi)
      #pragma unroll
      for (int i = 0; i < 4; ++i){
        const int row = m0 + wr*64 + mi*16 + lr*4 + i;
        #pragma unroll
        for (int ni = 0; ni < 4; ++ni){
          const int col = wc*64 + ni*16 + lc;
          dst[(size_t)row*128 + col] = acc[mi][ni][i];
        }
      }
  }
}

// ------- combine QK partials -> Qh/Ql/Kh/Kl, FUSED diag anchor + lpart zero -------
// Thread t handles (row = t>>5, cols c4*4..c4*4+3). Lanes c4 and c4+16 hold the
// same 4-col slice of q and k respectively -> dot via __shfl_xor(s,16), then
// 16-lane xor-reduce; lane c4==0 writes Mrow = q.k + 20. Lanes c4<8 zero lpart.
__global__ __launch_bounds__(256) void qk_combine_kernel(
    const float* __restrict__ QKpart, const float* __restrict__ bias_all,
    unsigned short* __restrict__ Qh, unsigned short* __restrict__ Ql,
    unsigned short* __restrict__ Kh, unsigned short* __restrict__ Kl,
    float* __restrict__ Mrow, float* __restrict__ lpart)
{
  const int t = blockIdx.x*256 + threadIdx.x;    // 0..262143 -> (row, c4)
  const int row = t >> 5, c4 = t & 31;
  const int col0 = c4*4;
  us4 h, lo;
  float s[4];
  #pragma unroll
  for (int i = 0; i < 4; ++i){
    const int col = col0 + i;
    const size_t o = (size_t)row*128 + col;
    s[i] = QKpart[o] + QKpart[(size_t)MROWS*128 + o]
         + QKpart[(size_t)2*MROWS*128 + o] + bias_all[col];
    const unsigned short hh = f2bf(s[i]);
    h[i]  = hh;
    lo[i] = f2bf(s[i] - bf2f(hh));
  }
  if (col0 < 64){
    *reinterpret_cast<us4*>(&Qh[(size_t)row*DH + col0]) = h;
    *reinterpret_cast<us4*>(&Ql[(size_t)row*DH + col0]) = lo;
  } else {
    *reinterpret_cast<us4*>(&Kh[(size_t)row*DH + col0 - 64]) = h;
    *reinterpret_cast<us4*>(&Kl[(size_t)row*DH + col0 - 64]) = lo;
  }
  // fused diag: q-lane c4 pairs with k-lane c4+16 (both in the same wave)
  float part = 0.f;
  #pragma unroll
  for (int i = 0; i < 4; ++i){
    const float o16 = __shfl_xor(s[i], 16);
    part += s[i]*o16;
  }
  #pragma unroll
  for (int m = 1; m < 16; m <<= 1) part += __shfl_xor(part, m);
  if (c4 == 0) Mrow[row] = part + 20.0f;
  if (c4 < 8)  lpart[(size_t)row*8 + c4] = 0.f;
}

// ---------------- QKV GEMM fallback (3-pass, used only if ws too small) ----------------
__global__ __launch_bounds__(256) void qkv_gemm_kernel(
    const unsigned short* __restrict__ xh, const unsigned short* __restrict__ xl,
    const unsigned short* __restrict__ Whi, const unsigned short* __restrict__ Wlo,
    const float* __restrict__ bias_all,
    unsigned short* __restrict__ Qh, unsigned short* __restrict__ Ql,
    unsigned short* __restrict__ Kh, unsigned short* __restrict__ Kl,
    unsigned short* __restrict__ Vt)
{
  __shared__ unsigned short tA[128*32];
  __shared__ unsigned short tB[128*32];
  const int bx = blockIdx.x;
  const int mtile = bx & 63;
  const int ntile = bx >> 6;
  const int m0 = mtile*128, n0 = ntile*128;
  const int tid = threadIdx.x;
  const int l = tid & 63, w = tid >> 6;
  const int lr = l >> 4, lc = l & 15;
  const int wr = w >> 1, wc = w & 1;

  f32x4 acc[4][4] = {};
  const int npass = (ntile == 0) ? 3 : 1;
  for (int pass = 0; pass < npass; ++pass){
    const unsigned short* Ab = (pass == 2) ? xl : xh;
    const unsigned short* Bb = (pass == 1) ? Wlo : (Whi + (size_t)n0*DM);
    for (int k0 = 0; k0 < DM; k0 += 32){
      __syncthreads();
      #pragma unroll
      for (int p = 0; p < 2; ++p){
        const int c   = tid + p*256;
        const int row = c >> 2, kq = c & 3;
        const unsigned short* ga = Ab + ((size_t)(m0+row)*DM + k0 + kq*8);
        const unsigned short* gb = Bb + ((size_t)row*DM     + k0 + kq*8);
        const int lbase = w*1024 + p*4096;
        __builtin_amdgcn_global_load_lds(
            (const __attribute__((address_space(1))) void*)ga,
            (__attribute__((address_space(3))) void*)((char*)tA + lbase), 16, 0, 0);
        __builtin_amdgcn_global_load_lds(
            (const __attribute__((address_space(1))) void*)gb,
            (__attribute__((address_space(3))) void*)((char*)tB + lbase), 16, 0, 0);
      }
      __syncthreads();
      bf16x8 af[4], bfr[4];
      #pragma unroll
      for (int mi = 0; mi < 4; ++mi){
        const int r = wr*64 + mi*16 + lc;
        af[mi] = *reinterpret_cast<const bf16x8*>((const char*)tA + r*64 + lr*16);
      }
      #pragma unroll
      for (int ni = 0; ni < 4; ++ni){
        const int r = wc*64 + ni*16 + lc;
        bfr[ni] = *reinterpret_cast<const bf16x8*>((const char*)tB + r*64 + lr*16);
      }
      #pragma unroll
      for (int mi = 0; mi < 4; ++mi)
        #pragma unroll
        for (int ni = 0; ni < 4; ++ni)
          acc[mi][ni] = mfma16(af[mi], bfr[ni], acc[mi][ni]);
    }
  }

  #pragma unroll
  for (int ni = 0; ni < 4; ++ni){
    const int col = n0 + wc*64 + ni*16 + lc;
    const float bias = bias_all[col];
    #pragma unroll
    for (int mi = 0; mi < 4; ++mi){
      const int rowb = m0 + wr*64 + mi*16 + lr*4;
      if (ntile > 0){
        const int vc = col - 128;
        const int b  = rowb >> 11;
        const int s  = rowb & 2047;
        us4 pk;
        #pragma unroll
        for (int i = 0; i < 4; ++i) pk[i] = f2bf(acc[mi][ni][i] + bias);
        *reinterpret_cast<us4*>(&Vt[((size_t)b*DM + vc)*SS + s]) = pk;
      } else {
        #pragma unroll
        for (int i = 0; i < 4; ++i){
          const int row = rowb + i;
          const float v = acc[mi][ni][i] + bias;
          const unsigned short h   = f2bf(v);
          const unsigned short lo2 = f2bf(v - bf2f(h));
          if (col < DH){
            Qh[(size_t)row*DH + col] = h;
            Ql[(size_t)row*DH + col] = lo2;
          } else {
            Kh[(size_t)row*DH + col - DH] = h;
            Kl[(size_t)row*DH + col - DH] = lo2;
          }
        }
      }
    }
  }
}

// ---------------- diag (fallback path only): anchor + zero lpart ----------------
__global__ __launch_bounds__(256) void diag_kernel(
    const unsigned short* __restrict__ Qh, const unsigned short* __restrict__ Ql,
    const unsigned short* __restrict__ Kh, const unsigned short* __restrict__ Kl,
    float* __restrict__ Mrow, float* __restrict__ lpart)
{
  const int r = blockIdx.x*256 + threadIdx.x;   // 0..8191
  float dot = 0.f;
  #pragma unroll
  for (int c = 0; c < 8; ++c){
    bf16x8 a  = *reinterpret_cast<const bf16x8*>(Qh + (size_t)r*DH + c*8);
    bf16x8 al = *reinterpret_cast<const bf16x8*>(Ql + (size_t)r*DH + c*8);
    bf16x8 bh = *reinterpret_cast<const bf16x8*>(Kh + (size_t)r*DH + c*8);
    bf16x8 bl = *reinterpret_cast<const bf16x8*>(Kl + (size_t)r*DH + c*8);
    #pragma unroll
    for (int j = 0; j < 8; ++j)
      dot += (bf2f((unsigned short)a[j]) + bf2f((unsigned short)al[j])) *
             (bf2f((unsigned short)bh[j]) + bf2f((unsigned short)bl[j]));
  }
  Mrow[r] = dot + 20.0f;
  #pragma unroll
  for (int kc = 0; kc < 8; ++kc) lpart[(size_t)r*8 + kc] = 0.f;
}

// ---------------- scores: P = exp(S - M_r) bf16, per-chunk row sums ----------------
__global__ __launch_bounds__(512) void scores_kernel(
    const unsigned short* __restrict__ Qh, const unsigned short* __restrict__ Ql,
    const unsigned short* __restrict__ Kh, const unsigned short* __restrict__ Kl,
    const float* __restrict__ Mrow,
    unsigned short* __restrict__ Pbuf, float* __restrict__ lpart)
{
  __shared__ float ws_s[8][32];
  const int t = blockIdx.x, b = blockIdx.y;
  int g = 0;
  while (g < 7 && 4*(g+1)*(g+2) <= t) ++g;
  const int base = 4*g*(g+1);
  const int qt = 8*g + (t - base)/(g+1);
  const int kc = (t - base)%(g+1);
  const int q0 = qt*32, kbase = kc*256;
  const int tid = threadIdx.x, l = tid & 63, w = tid >> 6;
  const int lr = l >> 4, lc = l & 15;
  const int kw0 = kbase + w*32;
  const float L2E = 1.4426950408889634f;

  bf16x8 qh[2][2], qlo[2][2], kh[2][2], kl2[2][2];
  #pragma unroll
  for (int qi = 0; qi < 2; ++qi)
    #pragma unroll
    for (int ks = 0; ks < 2; ++ks){
      const size_t off = (size_t)(b*SS + q0 + qi*16 + lc)*DH + ks*32 + lr*8;
      qh[qi][ks]  = *reinterpret_cast<const bf16x8*>(&Qh[off]);
      qlo[qi][ks] = *reinterpret_cast<const bf16x8*>(&Ql[off]);
    }
  #pragma unroll
  for (int ki = 0; ki < 2; ++ki)
    #pragma unroll
    for (int ks = 0; ks < 2; ++ks){
      const size_t off = (size_t)(b*SS + kw0 + ki*16 + lc)*DH + ks*32 + lr*8;
      kh[ki][ks]  = *reinterpret_cast<const bf16x8*>(&Kh[off]);
      kl2[ki][ks] = *reinterpret_cast<const bf16x8*>(&Kl[off]);
    }

  f32x4 sa[2][2] = {};
  #pragma unroll
  for (int qi = 0; qi < 2; ++qi)
    #pragma unroll
    for (int ki = 0; ki < 2; ++ki)
      #pragma unroll
      for (int ks = 0; ks < 2; ++ks){
        sa[qi][ki] = mfma16(qh[qi][ks],  kh[ki][ks],  sa[qi][ki]);
        sa[qi][ki] = mfma16(qh[qi][ks],  kl2[ki][ks], sa[qi][ki]);
        sa[qi][ki] = mfma16(qlo[qi][ks], kh[ki][ks],  sa[qi][ki]);
      }

  float Mv[2][4];
  #pragma unroll
  for (int qi = 0; qi < 2; ++qi)
    #pragma unroll
    for (int i = 0; i < 4; ++i)
      Mv[qi][i] = Mrow[b*SS + q0 + qi*16 + lr*4 + i];

  const bool diagblk = (kc == (qt >> 3));
  float psum[2][4] = {};
  #pragma unroll
  for (int qi = 0; qi < 2; ++qi)
    #pragma unroll
    for (int ki = 0; ki < 2; ++ki)
      #pragma unroll
      for (int i = 0; i < 4; ++i){
        const int qrow = qi*16 + lr*4 + i;
        const int kcol = w*32 + ki*16 + lc;
        float p;
        if (diagblk && (kbase + kcol > q0 + qrow)) p = 0.f;
        else p = exp2f((sa[qi][ki][i] - Mv[qi][i])*L2E);
        Pbuf[(size_t)(b*SS + q0 + qrow)*SS + kbase + kcol] = f2bf(p);
        psum[qi][i] += p;
      }

  #pragma unroll
  for (int qi = 0; qi < 2; ++qi)
    #pragma unroll
    for (int i = 0; i < 4; ++i){
      float s = psum[qi][i];
      #pragma unroll
      for (int m = 1; m < 16; m <<= 1) s += __shfl_xor(s, m);
      psum[qi][i] = s;
    }
  if (lc == 0){
    #pragma unroll
    for (int qi = 0; qi < 2; ++qi)
      #pragma unroll
      for (int i = 0; i < 4; ++i)
        ws_s[w][qi*16 + lr*4 + i] = psum[qi][i];
  }
  __syncthreads();
  if (tid < 32){
    float s = 0.f;
    #pragma unroll
    for (int w2 = 0; w2 < 8; ++w2) s += ws_s[w2][tid];
    lpart[(size_t)(b*SS + q0 + tid)*8 + kc] = s;
  }
}

// ------- PV GEMM + XCD-clustered + BK=64 paired pipeline; l-combine fused in epilogue ----
__global__ __launch_bounds__(256) void pv_kernel(
    const unsigned short* __restrict__ Pbuf, const unsigned short* __restrict__ Vt,
    const float* __restrict__ lpart, float* __restrict__ out)
{
  __shared__ unsigned short tA[2][2][128*32];
  __shared__ unsigned short tB[2][2][128*32];
  __shared__ float lfin_s[128];
  const int bx = blockIdx.x;           // 0..511
  const int xcd  = bx & 7;
  const int slot = bx >> 3;            // 0..63
  const int b   = xcd >> 1;
  const int ntg = xcd & 1;
  const int nt  = ntg*4 + (slot & 3);
  const int mt  = (slot < 32) ? (15 - (slot >> 2)) : ((slot - 32) >> 2);
  const int m0 = mt*128, n0 = nt*128;
  const int tid = threadIdx.x;
  const int l = tid & 63, w = tid >> 6;
  const int lr = l >> 4, lc = l & 15;
  const int wr = w >> 1, wc = w & 1;
  const int xq = (lr ^ ((lc >> 1) & 3))*16;

  const unsigned short* Ab = Pbuf + (size_t)(b*SS + m0)*SS;
  const unsigned short* Bb = Vt   + (size_t)(b*DM + n0)*SS;

  f32x4 acc[4][4] = {};
  const int NPAIR = (mt/2 + 1)*4;      // 64-K steps
  STAGE_TILES(tA[0][0], tB[0][0], Ab, Bb, SS, SS, 0);
  STAGE_TILES(tA[0][1], tB[0][1], Ab, Bb, SS, SS, 32);
  for (int t = 0; t < NPAIR; ++t){
    const int cur = t & 1;
    asm volatile("s_waitcnt vmcnt(0)" ::: "memory");
    __builtin_amdgcn_s_barrier();
    __builtin_amdgcn_sched_barrier(0);
    if (t + 1 < NPAIR){
      STAGE_TILES(tA[cur^1][0], tB[cur^1][0], Ab, Bb, SS, SS, (t+1)*64);
      STAGE_TILES(tA[cur^1][1], tB[cur^1][1], Ab, Bb, SS, SS, (t+1)*64 + 32);
    }
    COMPUTE_SUBTILE(tA[cur][0], tB[cur][0]);
    COMPUTE_SUBTILE(tA[cur][1], tB[cur][1]);
  }

  // fused l-combine: 128 threads each sum this tile's row partials
  if (tid < 128){
    const float* lp = lpart + ((size_t)(b*SS) + m0 + tid)*8;
    float s0 = 0.f;
    #pragma unroll
    for (int kc = 0; kc < 8; ++kc) s0 += lp[kc];
    lfin_s[tid] = s0;
  }
  __syncthreads();

  #pragma unroll
  for (int mi = 0; mi < 4; ++mi){
    #pragma unroll
    for (int i = 0; i < 4; ++i){
      const int rloc = wr*64 + mi*16 + lr*4 + i;
      const int row = m0 + rloc;
      const float linv = 1.0f / lfin_s[rloc];
      #pragma unroll
      for (int ni = 0; ni < 4; ++ni){
        const int col = n0 + wc*64 + ni*16 + lc;
        out[(size_t)(b*SS + row)*DM + col] = acc[mi][ni][i]*linv;
      }
    }
  }
}

// ---------------- launcher ----------------
extern "C" void kernel_launch(void* const* d_in, const int* in_sizes, int n_in,
                              void* d_out, int out_size, void* d_ws, size_t ws_size,
                              hipStream_t stream)
{
  const float* x  = (const float*)d_in[0];
  const float* wq = (const float*)d_in[1];
  const float* bq = (const float*)d_in[2];
  const float* wk = (const float*)d_in[3];
  const float* bk = (const float*)d_in[4];
  const float* wv = (const float*)d_in[5];
  const float* bv = (const float*)d_in[6];
  float* out = (float*)d_out;

  char* ws = (char*)d_ws;
  unsigned short* xh  = (unsigned short*)(ws + 0);          // 16,777,216
  unsigned short* xl  = (unsigned short*)(ws + 16777216);   // 16,777,216
  unsigned short* Pbuf= (unsigned short*)(ws + 0);          // 33,554,432 (alias)
  unsigned short* Whi = (unsigned short*)(ws + 33554432);   //  2,359,296
  unsigned short* Wlo = (unsigned short*)(ws + 35913728);   //    262,144
  float* bias_all     = (float*)(ws + 36175872);            //      4,608
  unsigned short* Qh  = (unsigned short*)(ws + 36180480);   //  1,048,576
  unsigned short* Ql  = (unsigned short*)(ws + 37229056);   //  1,048,576
  unsigned short* Kh  = (unsigned short*)(ws + 38277632);   //  1,048,576
  unsigned short* Kl  = (unsigned short*)(ws + 39326208);   //  1,048,576
  unsigned short* Vt  = (unsigned short*)(ws + 40374784);   // 16,777,216
  float* Mrow         = (float*)(ws + 57152000);            //     32,768
  float* lpart        = (float*)(ws + 57184768);            //    262,144
  const size_t QKPART_OFF = 57479680;
  float* QKpart       = (float*)(ws + QKPART_OFF);          // 12,582,912
  const size_t NEED = QKPART_OFF + (size_t)3*MROWS*128*4;   // 70,062,592

  hipLaunchKernelGGL(prep_kernel, dim3(2048), dim3(256), 0, stream,
                     x, wq, wk, wv, bq, bk, bv, xh, xl, Whi, Wlo, bias_all);
  if (ws_size >= NEED){
    hipLaunchKernelGGL(qkv_split_kernel, dim3(704), dim3(256), 0, stream,
                       xh, xl, Whi, Wlo, bias_all, Vt, QKpart);
    hipLaunchKernelGGL(qk_combine_kernel, dim3(1024), dim3(256), 0, stream,
                       QKpart, bias_all, Qh, Ql, Kh, Kl, Mrow, lpart);
  } else {
    hipLaunchKernelGGL(qkv_gemm_kernel, dim3(576), dim3(256), 0, stream,
                       xh, xl, Whi, Wlo, bias_all, Qh, Ql, Kh, Kl, Vt);
    hipLaunchKernelGGL(diag_kernel, dim3(32), dim3(256), 0, stream,
                       Qh, Ql, Kh, Kl, Mrow, lpart);
  }
  hipLaunchKernelGGL(scores_kernel, dim3(288, 4), dim3(512), 0, stream,
                     Qh, Ql, Kh, Kl, Mrow, Pbuf, lpart);
  hipLaunchKernelGGL(pv_kernel, dim3(512), dim3(256), 0, stream, Pbuf, Vt, lpart, out);
}